// Round 13
// baseline (634.561 us; speedup 1.0000x reference)
//
#include <hip/hip_runtime.h>

// ---------------------------------------------------------------------------
// Transformer-XL decoder layer on MI355X (gfx950).
// QLEN=1024, MLEN=1024, KLEN=2048, BSZ=4, DMODEL=1024, NHEAD=16, DHEAD=64, DFF=4096
// Round 19: round-18 resubmit (compile fix: removed the forward-referenced
// outp_helper). attn = v6 byte-exact (R-prefetch spilled; attn ledger 7
// failed restructures -> closed at 214 us). GEMM: 2-phase double-buffer
// (gemm_db) for R/Wo/FF2 -- stage(t+1) issued BEFORE compute(t), ONE
// __syncthreads() per K-step (drain lands after a full compute-phase of
// latency hiding). WN=2: 48KB -> 3 blocks/CU; WN=1: 40KB -> 4/CU (round-7's
// 3-buf failed at 2/CU -- occupancy floor respected). QKV/FF1 keep the
// proven single-buffer WN=4 path. Rest = round-16 (612.1 us).
// rel_shift fact: BD[i,j] = BDu[i, j+1023-i] for j <= i+1024; rest is masked.
// ---------------------------------------------------------------------------

typedef __bf16 bf16x8 __attribute__((ext_vector_type(8)));
typedef float f32x4 __attribute__((ext_vector_type(4)));

#define DEVI __device__ __forceinline__

DEVI unsigned short f2bf(float f) {
  union { float f; unsigned int u; } v;
  v.f = f;
  unsigned int u = v.u;
  u += 0x7fffu + ((u >> 16) & 1u);  // RNE
  return (unsigned short)(u >> 16);
}

// async global->LDS, 16 B per lane; lds dest is the wave-uniform base.
DEVI void load16(const unsigned short* g, unsigned short* l) {
  __builtin_amdgcn_global_load_lds(
      (const __attribute__((address_space(1))) unsigned int*)g,
      (__attribute__((address_space(3))) unsigned int*)l, 16, 0, 0);
}

// ---------------------------------------------------------------------------
// fused f32 -> bf16 convert for memories / word_embed / pos_embed
// ---------------------------------------------------------------------------
__global__ __launch_bounds__(256) void cvt_all_kernel(
    const float* __restrict__ mem, const float* __restrict__ we,
    const float* __restrict__ pe, unsigned short* __restrict__ catb,
    unsigned short* __restrict__ posb) {
  const int b = blockIdx.x;
  const float* in;
  unsigned short* out;
  int idx;
  if (b < 4096) {
    in = mem; out = catb; idx = b;
  } else if (b < 8192) {
    in = we; out = catb + (size_t)4096 * 1024; idx = b - 4096;
  } else {
    in = pe; out = posb; idx = b - 8192;
  }
  const size_t i = ((size_t)idx * 256 + threadIdx.x) * 4;
  float4 v = *(const float4*)(in + i);
  ushort4 o;
  o.x = f2bf(v.x);
  o.y = f2bf(v.y);
  o.z = f2bf(v.z);
  o.w = f2bf(v.w);
  *(ushort4*)(out + i) = o;
}

// ---------------------------------------------------------------------------
// fused transpose+convert for all 5 weight matrices: out[c][r] = bf16(in[r][c])
// block ranges: [0,768) W_qkv, [768,1024) W_r, [1024,1280) W_o,
// [1280,2304) W_ff1, [2304,3328) W_ff2
// ---------------------------------------------------------------------------
__global__ __launch_bounds__(256) void transpose_all_kernel(
    const float* __restrict__ Wqkv, const float* __restrict__ Wr,
    const float* __restrict__ Wo, const float* __restrict__ Wff1,
    const float* __restrict__ Wff2, unsigned short* __restrict__ Tqkv,
    unsigned short* __restrict__ Tr, unsigned short* __restrict__ To,
    unsigned short* __restrict__ Tff1, unsigned short* __restrict__ Tff2) {
  __shared__ unsigned short t[64][72];
  const int b = blockIdx.x;
  const float* in;
  unsigned short* out;
  int ntx, R, C, local;
  if (b < 768) {
    in = Wqkv; out = Tqkv; ntx = 48; R = 1024; C = 3072; local = b;
  } else if (b < 1024) {
    in = Wr; out = Tr; ntx = 16; R = 1024; C = 1024; local = b - 768;
  } else if (b < 1280) {
    in = Wo; out = To; ntx = 16; R = 1024; C = 1024; local = b - 1024;
  } else if (b < 2304) {
    in = Wff1; out = Tff1; ntx = 64; R = 1024; C = 4096; local = b - 1280;
  } else {
    in = Wff2; out = Tff2; ntx = 16; R = 4096; C = 1024; local = b - 2304;
  }
  const int r0 = (local / ntx) * 64, c0 = (local % ntx) * 64;
  const int tid = threadIdx.x;
#pragma unroll
  for (int it = 0; it < 4; ++it) {
    int f = tid + 256 * it;
    int r = f >> 4;
    int c4 = (f & 15) << 2;
    float4 v = *(const float4*)(in + (size_t)(r0 + r) * C + c0 + c4);
    t[c4 + 0][r] = f2bf(v.x);
    t[c4 + 1][r] = f2bf(v.y);
    t[c4 + 2][r] = f2bf(v.z);
    t[c4 + 3][r] = f2bf(v.w);
  }
  __syncthreads();
#pragma unroll
  for (int it = 0; it < 4; ++it) {
    int f = tid + 256 * it;
    int cc = f >> 4;
    int r4 = (f & 15) << 2;
    ushort4 o;
    o.x = t[cc][r4 + 0];
    o.y = t[cc][r4 + 1];
    o.z = t[cc][r4 + 2];
    o.w = t[cc][r4 + 3];
    *(ushort4*)(out + (size_t)(c0 + cc) * R + r0 + r4) = o;
  }
}

// ---------------------------------------------------------------------------
// GEMM args + shared epilogue (scatter math identical to the proven kernel).
// Fragment-major layout (per 64-row slab, stride 131072 shorts):
//   AC/BD-type: idx = (t16*2+half)*512 + (quad*16+l15)*8 + e
//               value = X[row=t16*16+l15][col=half*32+quad*8+e]
//   PV-type V:  idx = jt*8192 + (ks*4+nto)*512 + (quad*16+l15)*8 + e
//               value = V[j=jt*128+ks*32+quad*8+e][d=nto*16+l15]
// ---------------------------------------------------------------------------
struct GemmArgs {
  const unsigned short* A;   // bf16 [M][K]
  const unsigned short* Bt;  // bf16 [N][K]
  int Ks;                    // K-loop extent (== K unless split-K)
  int M, N, K;
  const float* p0;  // bias_q (EPI0) / bias (EPI2)
  const float* p1;  // bias_k (EPI0)
  const float* resid;
  float* outF;
  unsigned short* o0;  // QQ / Rf / bf16-out
  unsigned short* o1;  // QK
  unsigned short* o2;  // Kf
  unsigned short* o3;  // Vf
  int relu;
  int partial;  // EPI2: store raw f32 partial at outF + z*M*N
};

template <int EPI>
DEVI void epi_store(const GemmArgs& ga, int bz, int row, int col, float val) {
  if constexpr (EPI == 0) {
    const int seq = row >> 2, b = row & 3;  // cat flat row = seq*BSZ + b
    if (col < 1024) {
      if (seq >= 1024) {
        const int nh = col >> 6, d = col & 63;
        const size_t o = ((size_t)((b * 16 + nh) * 1024 + (seq - 1024))) * 64 + d;
        ga.o0[o] = f2bf(val + ga.p0[col]);  // q + bias_q
        ga.o1[o] = f2bf(val + ga.p1[col]);  // q + bias_k
      }
    } else if (col < 2048) {
      // K -> fragment-major
      const int c = col - 1024, nh = c >> 6, d = c & 63, bn = b * 16 + nh;
      const size_t o = (size_t)bn * 131072 +
                       (size_t)(((seq >> 4) * 2 + (d >> 5)) * 512) +
                       ((((d >> 3) & 3) * 16 + (seq & 15)) * 8) + (d & 7);
      ga.o2[o] = f2bf(val);
    } else {
      // V -> fragment-major (PV-type)
      const int c = col - 2048, nh = c >> 6, d = c & 63, bn = b * 16 + nh;
      const size_t o = (size_t)bn * 131072 + (size_t)((seq >> 7) * 8192) +
                       ((((seq >> 5) & 3) * 4 + (d >> 4)) * 512) +
                       ((((seq >> 3) & 3) * 16 + (d & 15)) * 8) + (seq & 7);
      ga.o3[o] = f2bf(val);
    }
  } else if constexpr (EPI == 1) {
    // R -> fragment-major per head
    const int nh = col >> 6, d = col & 63, t = row;
    const size_t o = (size_t)nh * 131072 +
                     (size_t)(((t >> 4) * 2 + (d >> 5)) * 512) +
                     ((((d >> 3) & 3) * 16 + (t & 15)) * 8) + (d & 7);
    ga.o0[o] = f2bf(val);
  } else {
    if (ga.partial) {
      ga.outF[(size_t)bz * ((size_t)ga.M * ga.N) + (size_t)row * ga.N + col] = val;
    } else {
      if (ga.p0) val += ga.p0[col];
      if (ga.resid) val += ga.resid[(size_t)row * ga.N + col];
      if (ga.relu) val = fmaxf(val, 0.f);
      if (ga.outF) ga.outF[(size_t)row * ga.N + col] = val;
      if (ga.o0) ga.o0[(size_t)row * ga.N + col] = f2bf(val);
    }
  }
}

constexpr int BM = 128, BK = 64;

// ---------------------------------------------------------------------------
// Single-buffered GEMM (proven path): QKV (EPI0, flat active grid) and FF1.
// ---------------------------------------------------------------------------
template <int EPI, int WN = 4>
__global__ __launch_bounds__(256, 4) void gemm_kernel(GemmArgs ga) {
  constexpr int BN_ = WN * 32;
  __shared__ __align__(16) unsigned short As[BM * BK];
  __shared__ __align__(16) unsigned short Bs[BN_ * BK];

  int m0, n0;
  if constexpr (EPI == 0) {
    // flat enumeration of the 1280 active tiles (skip q-cols x memory-rows)
    const int flat = blockIdx.x;
    int mt_, nt_;
    if (flat < 1024) {         // K/V columns: ntile 8..23, all 64 m-tiles
      mt_ = flat >> 4;
      nt_ = 8 + (flat & 15);
    } else {                   // q columns: ntile 0..7, m-tiles 32..63
      const int f2 = flat - 1024;
      mt_ = 32 + (f2 >> 3);
      nt_ = f2 & 7;
    }
    m0 = mt_ * 128;
    n0 = nt_ * 128;
  } else {
    n0 = blockIdx.x * BN_;
    m0 = blockIdx.y * BM;
  }
  const int bz = blockIdx.z;
  const int tid = threadIdx.x;
  const int lane = tid & 63;
  const int wv = tid >> 6;
  const int l15 = lane & 15;
  const int quad = lane >> 4;
  const int wm = wv & 1, wn = wv >> 1;
  const int K = ga.K;
  const int Ks = ga.Ks;
  const int r8 = lane >> 3;
  const int sc = (lane & 7) ^ r8;

  const f32x4 fzero = {0.f, 0.f, 0.f, 0.f};
  f32x4 acc[4][WN];
#pragma unroll
  for (int i = 0; i < 4; ++i)
#pragma unroll
    for (int j = 0; j < WN; ++j) acc[i][j] = fzero;

  const unsigned short* Ab =
      ga.A + (size_t)(m0 + 32 * wv + r8) * K + sc * 8 + (size_t)bz * Ks;
  const unsigned short* Bb =
      ga.Bt + (size_t)(n0 + (BN_ / 4) * wv + r8) * K + sc * 8 + (size_t)bz * Ks;
  const int h7 = l15 & 7;

  for (int k0 = 0; k0 < Ks; k0 += BK) {
    __syncthreads();
#pragma unroll
    for (int it = 0; it < 4; ++it)
      load16(Ab + (size_t)(8 * it) * K + k0, &As[(32 * wv + 8 * it) * 64]);
#pragma unroll
    for (int it = 0; it < BN_ / 32; ++it)
      load16(Bb + (size_t)(8 * it) * K + k0, &Bs[((BN_ / 4) * wv + 8 * it) * 64]);
    __syncthreads();
#pragma unroll
    for (int ks = 0; ks < 2; ++ks) {
      bf16x8 af[4], bg[WN];
#pragma unroll
      for (int mt = 0; mt < 4; ++mt)
        af[mt] = *(const bf16x8*)&As[(wm * 64 + mt * 16 + l15) * 64 +
                                     (((ks * 4 + quad) ^ h7) * 8)];
#pragma unroll
      for (int nt = 0; nt < WN; ++nt)
        bg[nt] = *(const bf16x8*)&Bs[(wn * (WN * 16) + nt * 16 + l15) * 64 +
                                     (((ks * 4 + quad) ^ h7) * 8)];
#pragma unroll
      for (int mt = 0; mt < 4; ++mt)
#pragma unroll
        for (int nt = 0; nt < WN; ++nt)
          acc[mt][nt] =
              __builtin_amdgcn_mfma_f32_16x16x32_bf16(af[mt], bg[nt], acc[mt][nt], 0, 0, 0);
    }
  }

#pragma unroll
  for (int mt = 0; mt < 4; ++mt)
#pragma unroll
    for (int nt = 0; nt < WN; ++nt)
#pragma unroll
      for (int r = 0; r < 4; ++r) {
        const int row = m0 + wm * 64 + mt * 16 + quad * 4 + r;
        const int col = n0 + wn * (WN * 16) + nt * 16 + l15;
        epi_store<EPI>(ga, bz, row, col, acc[mt][nt][r]);
      }
}

// ---------------------------------------------------------------------------
// 2-phase double-buffered GEMM: stage(t+1) BEFORE compute(t), one
// __syncthreads() per K-step (drain happens after compute hides the
// latency). WN=2 -> 48KB LDS = 3 blocks/CU; WN=1 -> 40KB = 4/CU.
// Used for R-proj / Wo / FF2 (thin GEMMs).
// ---------------------------------------------------------------------------
template <int EPI, int WN = 2>
__global__ __launch_bounds__(256, 4) void gemm_db(GemmArgs ga) {
  constexpr int BN_ = WN * 32;
  __shared__ __align__(16) unsigned short As[2][BM * BK];
  __shared__ __align__(16) unsigned short Bs[2][BN_ * BK];

  const int n0 = blockIdx.x * BN_;
  const int m0 = blockIdx.y * BM;
  const int bz = blockIdx.z;
  const int tid = threadIdx.x;
  const int lane = tid & 63;
  const int wv = tid >> 6;
  const int l15 = lane & 15;
  const int quad = lane >> 4;
  const int wm = wv & 1, wn = wv >> 1;
  const int K = ga.K;
  const int Ks = ga.Ks;
  const int r8 = lane >> 3;
  const int sc = (lane & 7) ^ r8;
  const int h7 = l15 & 7;

  const f32x4 fzero = {0.f, 0.f, 0.f, 0.f};
  f32x4 acc[4][WN];
#pragma unroll
  for (int i = 0; i < 4; ++i)
#pragma unroll
    for (int j = 0; j < WN; ++j) acc[i][j] = fzero;

  const unsigned short* Ab =
      ga.A + (size_t)(m0 + 32 * wv + r8) * K + sc * 8 + (size_t)bz * Ks;
  const unsigned short* Bb =
      ga.Bt + (size_t)(n0 + (BN_ / 4) * wv + r8) * K + sc * 8 + (size_t)bz * Ks;

  auto stage = [&](int k0, int bi) {
#pragma unroll
    for (int it = 0; it < 4; ++it)
      load16(Ab + (size_t)(8 * it) * K + k0, &As[bi][(32 * wv + 8 * it) * 64]);
#pragma unroll
    for (int it = 0; it < BN_ / 32; ++it)
      load16(Bb + (size_t)(8 * it) * K + k0, &Bs[bi][((BN_ / 4) * wv + 8 * it) * 64]);
  };

  stage(0, 0);
  __syncthreads();  // drains prologue loads

  int buf = 0;
  for (int k0 = 0; k0 < Ks; k0 += BK) {
    if (k0 + BK < Ks) stage(k0 + BK, buf ^ 1);  // overlaps compute below
#pragma unroll
    for (int ks = 0; ks < 2; ++ks) {
      bf16x8 af[4], bg[WN];
#pragma unroll
      for (int mt = 0; mt < 4; ++mt)
        af[mt] = *(const bf16x8*)&As[buf][(wm * 64 + mt * 16 + l15) * 64 +
                                         (((ks * 4 + quad) ^ h7) * 8)];
#pragma unroll
      for (int nt = 0; nt < WN; ++nt)
        bg[nt] = *(const bf16x8*)&Bs[buf][(wn * (WN * 16) + nt * 16 + l15) * 64 +
                                          (((ks * 4 + quad) ^ h7) * 8)];
#pragma unroll
      for (int mt = 0; mt < 4; ++mt)
#pragma unroll
        for (int nt = 0; nt < WN; ++nt)
          acc[mt][nt] =
              __builtin_amdgcn_mfma_f32_16x16x32_bf16(af[mt], bg[nt], acc[mt][nt], 0, 0, 0);
    }
    __syncthreads();  // one barrier/step: drains next-tile loads + read fence
    buf ^= 1;
  }

#pragma unroll
  for (int mt = 0; mt < 4; ++mt)
#pragma unroll
    for (int nt = 0; nt < WN; ++nt)
#pragma unroll
      for (int r = 0; r < 4; ++r) {
        const int row = m0 + wm * 64 + mt * 16 + quad * 4 + r;
        const int col = n0 + wn * (WN * 16) + nt * 16 + l15;
        epi_store<EPI>(ga, bz, row, col, acc[mt][nt][r]);
      }
}

// ---------------------------------------------------------------------------
// Flash attention with Transformer-XL relative-position term (v6, round-0
// byte-exact). Barrier-free; one wave per 16-row i-tile; 4 blocks/CU. All
// K/V/R B-operands are coalesced dwordx4 loads from fragment-major global
// slabs (L2-resident; block%8 == bn%8 keeps each XCD at 8 slabs). The 4
// waves of a block scan the same j-chunks in lockstep -> L1 line sharing.
// Fixed-max softmax; l reduced once at epilogue; P hop via wave-private LDS.
// ---------------------------------------------------------------------------
constexpr int P_LD = 136;            // p_s row stride (bf16 elems)
constexpr float CEXP = 0.18033688f;  // 0.125 * log2(e)

__global__ __launch_bounds__(256, 4) void attn_kernel(
    const unsigned short* __restrict__ QQ, const unsigned short* __restrict__ QK,
    const unsigned short* __restrict__ Kf, const unsigned short* __restrict__ Vf,
    const unsigned short* __restrict__ Rf, unsigned short* __restrict__ AVb) {
  __shared__ __align__(16) unsigned short p_s[4][16 * P_LD];

  const int tid = threadIdx.x;
  const int lane = tid & 63;
  const int wv = tid >> 6;
  const int l15 = lane & 15;
  const int quad = lane >> 4;
  const int bn = blockIdx.x;                   // (b,n): block%8 == bn%8 -> XCD locality
  const int iw = (blockIdx.y * 4 + wv) * 16;   // wave-private 16-row i-tile
  const int nh = bn & 15;
  const int bb = bn >> 4;
  unsigned short* pw = &p_s[wv][0];

  const unsigned short* kf = Kf + (size_t)bn * 131072;
  const unsigned short* vf = Vf + (size_t)bn * 131072;
  const unsigned short* rf = Rf + (size_t)nh * 131072;

  // Q fragments in registers: rows [iw, iw+16)
  const size_t qoff = (size_t)bn * (1024 * 64) + (size_t)(iw + l15) * 64;
  const bf16x8 qq0 = *(const bf16x8*)(QQ + qoff + quad * 8);
  const bf16x8 qq1 = *(const bf16x8*)(QQ + qoff + 32 + quad * 8);
  const bf16x8 qk0 = *(const bf16x8*)(QK + qoff + quad * 8);
  const bf16x8 qk1 = *(const bf16x8*)(QK + qoff + 32 + quad * 8);

  const f32x4 fzero = {0.f, 0.f, 0.f, 0.f};
  f32x4 o_acc[4];
#pragma unroll
  for (int i = 0; i < 4; ++i) o_acc[i] = fzero;
  float lsum[4] = {0.f, 0.f, 0.f, 0.f};

  const int lane8 = lane * 8;
  const int jmax = iw + 15 + 1024;  // beyond this, tiles are fully masked
  for (int j0 = 0; j0 <= jmax; j0 += 128) {
    // BDu: window base t16b = (j0 + 1008 - iw)/16; 9 fragment tiles, clamped
    const int t16b = (j0 >> 4) + 63 - (iw >> 4);
    f32x4 bd[9];
#pragma unroll
    for (int ct = 0; ct < 9; ++ct) {
      int tg = t16b + ct;
      tg = (tg < 127) ? tg : 127;  // rows >=2048 only feed masked cols
      const unsigned short* rb = rf + (size_t)(tg * 1024) + lane8;
      bf16x8 b0 = *(const bf16x8*)rb;
      bf16x8 b1 = *(const bf16x8*)(rb + 512);
      f32x4 c = fzero;
      c = __builtin_amdgcn_mfma_f32_16x16x32_bf16(qk0, b0, c, 0, 0, 0);
      c = __builtin_amdgcn_mfma_f32_16x16x32_bf16(qk1, b1, c, 0, 0, 0);
      bd[ct] = c;
    }

    // AC = (q+bias_q) @ K^T
    const int ntb = j0 >> 4;
    f32x4 sv[8];
#pragma unroll
    for (int nt = 0; nt < 8; ++nt) {
      const unsigned short* kb = kf + (size_t)((ntb + nt) * 1024) + lane8;
      bf16x8 b0 = *(const bf16x8*)kb;
      bf16x8 b1 = *(const bf16x8*)(kb + 512);
      f32x4 c = fzero;
      c = __builtin_amdgcn_mfma_f32_16x16x32_bf16(qq0, b0, c, 0, 0, 0);
      c = __builtin_amdgcn_mfma_f32_16x16x32_bf16(qq1, b1, c, 0, 0, 0);
      sv[nt] = c;
    }

    // rel-shift (in-quad rotate) + fixed-max exp + per-lane l accumulation
#pragma unroll
    for (int r = 0; r < 4; ++r) {
      const int il = quad * 4 + r;  // tile-local row
      const int u = l15 + 15 - il;  // 0..30
      const int srcl = (lane & 48) | (u & 15);
      float w[9];
#pragma unroll
      for (int ct = 0; ct < 9; ++ct) w[ct] = __shfl(bd[ct][r], srcl, 64);
      const int ig = iw + il;
#pragma unroll
      for (int nt = 0; nt < 8; ++nt) {
        const float bdv = (u & 16) ? w[nt + 1] : w[nt];
        const int jg = j0 + nt * 16 + l15;
        float p = exp2f((sv[nt][r] + bdv) * CEXP);
        p = (jg > ig + 1024) ? 0.f : p;  // select: garbage/NaN-safe
        lsum[r] += p;
        pw[il * P_LD + nt * 16 + l15] = f2bf(p);
      }
    }

    // O += P @ V (K-dim = 128); V fragments coalesced from global
    const unsigned short* vb = vf + (size_t)((j0 >> 7) * 8192) + lane8;
#pragma unroll
    for (int ks = 0; ks < 4; ++ks) {
      bf16x8 ap = *(const bf16x8*)&pw[l15 * P_LD + ks * 32 + quad * 8];
#pragma unroll
      for (int nto = 0; nto < 4; ++nto) {
        bf16x8 bv = *(const bf16x8*)(vb + (ks * 4 + nto) * 512);
        o_acc[nto] = __builtin_amdgcn_mfma_f32_16x16x32_bf16(ap, bv, o_acc[nto], 0, 0, 0);
      }
    }
  }

  // reduce l across the 16 lanes holding each row, then write O/l
  float linv[4];
#pragma unroll
  for (int r = 0; r < 4; ++r) {
    float l = lsum[r];
    l += __shfl_xor(l, 1, 64);
    l += __shfl_xor(l, 2, 64);
    l += __shfl_xor(l, 4, 64);
    l += __shfl_xor(l, 8, 64);
    linv[r] = 1.f / l;
  }
#pragma unroll
  for (int nto = 0; nto < 4; ++nto) {
#pragma unroll
    for (int r = 0; r < 4; ++r) {
      const int ig = iw + quad * 4 + r;
      const int d = nto * 16 + l15;
      const float val = o_acc[nto][r] * linv[r];
      AVb[(size_t)(ig * 4 + bb) * 1024 + nh * 64 + d] = f2bf(val);
    }
  }
}

// ---------------------------------------------------------------------------
// LayerNorm over rows of 1024 with fused split-K reduce:
// pre[c] = x0[c] + x1[c] + bias[c]? + resid[c]?; then normalize.
// ---------------------------------------------------------------------------
__global__ __launch_bounds__(256) void ln_sum_kernel(
    const float* __restrict__ x0, const float* __restrict__ x1,
    const float* __restrict__ bias, const float* __restrict__ resid,
    const float* __restrict__ g, const float* __restrict__ bta,
    float* __restrict__ outF, unsigned short* __restrict__ outB) {
  const int row = blockIdx.x;
  const int tid = threadIdx.x;
  const size_t off = (size_t)row * 1024 + tid * 4;
  float4 v = *(const float4*)(x0 + off);
  const float4 w = *(const float4*)(x1 + off);
  v.x += w.x; v.y += w.y; v.z += w.z; v.w += w.w;
  if (bias) {
    const float4 b = *(const float4*)(bias + tid * 4);
    v.x += b.x; v.y += b.y; v.z += b.z; v.w += b.w;
  }
  if (resid) {
    const float4 rr = *(const float4*)(resid + off);
    v.x += rr.x; v.y += rr.y; v.z += rr.z; v.w += rr.w;
  }
  float s = v.x + v.y + v.z + v.w;
  float ss = v.x * v.x + v.y * v.y + v.z * v.z + v.w * v.w;
#pragma unroll
  for (int off2 = 1; off2 < 64; off2 <<= 1) {
    s += __shfl_xor(s, off2, 64);
    ss += __shfl_xor(ss, off2, 64);
  }
  __shared__ float red[8];
  const int wv = tid >> 6;
  if ((tid & 63) == 0) {
    red[wv] = s;
    red[4 + wv] = ss;
  }
  __syncthreads();
  s = red[0] + red[1] + red[2] + red[3];
  ss = red[4] + red[5] + red[6] + red[7];
  const float mu = s * (1.f / 1024.f);
  const float var = ss * (1.f / 1024.f) - mu * mu;
  const float rs = rsqrtf(var + 1e-5f);
  const float vv[4] = {v.x, v.y, v.z, v.w};
#pragma unroll
  for (int u = 0; u < 4; ++u) {
    const int c = tid * 4 + u;
    const float y = (vv[u] - mu) * rs * g[c] + bta[c];
    if (outF) outF[(size_t)row * 1024 + c] = y;
    if (outB) outB[(size_t)row * 1024 + c] = f2bf(y);
  }
}

// ---------------------------------------------------------------------------
extern "C" void kernel_launch(void* const* d_in, const int* in_sizes, int n_in,
                              void* d_out, int out_size, void* d_ws, size_t ws_size,
                              hipStream_t stream) {
  (void)in_sizes; (void)n_in; (void)out_size; (void)ws_size;
  const float* word_embed = (const float*)d_in[0];
  const float* pos_embed = (const float*)d_in[1];
  const float* bias_q = (const float*)d_in[2];
  const float* bias_k = (const float*)d_in[3];
  const float* memories = (const float*)d_in[4];
  const float* W_qkv = (const float*)d_in[5];
  const float* W_r = (const float*)d_in[6];
  const float* W_o = (const float*)d_in[7];
  const float* ln1_g = (const float*)d_in[8];
  const float* ln1_b = (const float*)d_in[9];
  const float* W_ff1 = (const float*)d_in[10];
  const float* b_ff1 = (const float*)d_in[11];
  const float* W_ff2 = (const float*)d_in[12];
  const float* b_ff2 = (const float*)d_in[13];
  const float* ln2_g = (const float*)d_in[14];
  const float* ln2_b = (const float*)d_in[15];
  float* out = (float*)d_out;

  char* ws = (char*)d_ws;
  unsigned short* QQ = (unsigned short*)(ws + 0);           // 8 MB
  unsigned short* QK = (unsigned short*)(ws + 8388608);     // 8 MB
  unsigned short* Kf = (unsigned short*)(ws + 16777216);    // 16 MB (frag-major)
  unsigned short* Vf = (unsigned short*)(ws + 50331648);    // 16 MB (frag-major)
  unsigned short* Rf = (unsigned short*)(ws + 67108864);    // 4 MB (frag-major)
  unsigned short* AVb = (unsigned short*)(ws + 71303168);   // 8 MB
  float* OUT1 = (float*)(ws + 96468992);                    // 16 MB
  unsigned short* OUT1b = (unsigned short*)(ws + 113246208);  // 8 MB
  unsigned short* Wqkv_t = (unsigned short*)(ws + 121634816); // 6 MB
  unsigned short* Wr_t = (unsigned short*)(ws + 127926272);   // 2 MB
  unsigned short* Wo_t = (unsigned short*)(ws + 130023424);   // 2 MB
  unsigned short* Wff1_t = (unsigned short*)(ws + 132120576); // 8 MB
  unsigned short* Wff2_t = (unsigned short*)(ws + 140509184); // 8 MB
  unsigned short* Catb = (unsigned short*)(ws + 79691776);    // 16 MB (pre-attn)
  unsigned short* Posb = (unsigned short*)(ws + 96468992);    // aliases OUT1 (pre-LN1)
  unsigned short* H = (unsigned short*)(ws + 0);              // 32 MB, aliases QQ/QK/Kf
  // split-K partial buffers (f32, 2 x 16 MB each), in post-attn dead regions:
  float* Pwo = (float*)(ws + 33554432);   // 33.5..67.1 MB: free gap + Vf (dead post-attn)
  float* Pff = (float*)(ws + 50331648);   // 50.3..83.9 MB: Vf + Rf + AVb (dead post-Wo) + Catb head

  const dim3 blk(256);

  // fused prologue: 1 cvt launch + 1 transpose launch
  cvt_all_kernel<<<10240, blk, 0, stream>>>(memories, word_embed, pos_embed, Catb, Posb);
  transpose_all_kernel<<<3328, blk, 0, stream>>>(W_qkv, W_r, W_o, W_ff1, W_ff2,
                                                 Wqkv_t, Wr_t, Wo_t, Wff1_t, Wff2_t);

  // QKV projection: M=8192, N=3072, K=1024; flat 1280-block active grid
  {
    GemmArgs a{};
    a.A = Catb;
    a.Bt = Wqkv_t;
    a.M = 8192; a.N = 3072; a.K = 1024; a.Ks = 1024;
    a.p0 = bias_q; a.p1 = bias_k;
    a.o0 = QQ; a.o1 = QK; a.o2 = Kf; a.o3 = Vf;
    gemm_kernel<0><<<dim3(1280), blk, 0, stream>>>(a);
  }
  // R projection: WN=1 double-buffered (40KB LDS, 4/CU), 512 blocks
  {
    GemmArgs a{};
    a.A = Posb;
    a.Bt = Wr_t;
    a.M = 2048; a.N = 1024; a.K = 1024; a.Ks = 1024;
    a.o0 = Rf;
    gemm_db<1, 1><<<dim3(32, 16), blk, 0, stream>>>(a);
  }

  // attention: grid (bn=64, itile=16), 1024 blocks, 4/CU, barrier-free
  attn_kernel<<<dim3(64, 16), blk, 0, stream>>>(QQ, QK, Kf, Vf, Rf, AVb);

  // W_o projection, split-K=2, WN=2 double-buffered (48KB, 3/CU)
  {
    GemmArgs a{};
    a.A = AVb;
    a.Bt = Wo_t;
    a.M = 4096; a.N = 1024; a.K = 1024; a.Ks = 512;
    a.outF = Pwo;
    a.partial = 1;
    gemm_db<2, 2><<<dim3(16, 32, 2), blk, 0, stream>>>(a);
  }
  // LN1 with fused reduce: P0+P1 + word_embed resid
  ln_sum_kernel<<<4096, blk, 0, stream>>>(Pwo, Pwo + (size_t)4096 * 1024, nullptr,
                                          word_embed, ln1_g, ln1_b, OUT1, OUT1b);

  // FF1 (BN=128, 1024 blocks, single-buffer proven path)
  {
    GemmArgs a{};
    a.A = OUT1b;
    a.Bt = Wff1_t;
    a.M = 4096; a.N = 4096; a.K = 1024; a.Ks = 1024;
    a.p0 = b_ff1;
    a.relu = 1;
    a.o0 = H;
    gemm_kernel<2><<<dim3(32, 32), blk, 0, stream>>>(a);
  }
  // FF2, split-K=2, WN=2 double-buffered (48KB, 3/CU), K=2048 each
  {
    GemmArgs a{};
    a.A = H;
    a.Bt = Wff2_t;
    a.M = 4096; a.N = 1024; a.K = 4096; a.Ks = 2048;
    a.outF = Pff;
    a.partial = 1;
    gemm_db<2, 2><<<dim3(16, 32, 2), blk, 0, stream>>>(a);
  }
  // LN2 with fused reduce: Q0+Q1 + b_ff2 + OUT1 resid
  ln_sum_kernel<<<4096, blk, 0, stream>>>(Pff, Pff + (size_t)4096 * 1024, b_ff2,
                                          OUT1, ln2_g, ln2_b, out, nullptr);
}

// Round 14
// 579.256 us; speedup vs baseline: 1.0955x; 1.0955x over previous
//
#include <hip/hip_runtime.h>

// ---------------------------------------------------------------------------
// Transformer-XL decoder layer on MI355X (gfx950).
// QLEN=1024, MLEN=1024, KLEN=2048, BSZ=4, DMODEL=1024, NHEAD=16, DHEAD=64, DFF=4096
// Round 20: revert gemm_db (634.6 us: 48KB LDS -> 3 blocks/CU; THIRD
// confirmation that occupancy beats pipelining on these thin shapes).
// Back to round-16 config (612.1 us, proven twice) + ONE change: T1
// XCD-chunked bijective swizzle on the QKV flat grid
// (flat = (b&7)*160 + b>>3; 1280%8==0). Each XCD then owns a contiguous
// 160-tile chunk: 10 A-panels streamed once, 16 B-panels (4MB) L2-resident
// and reused across all 10 mt-groups. Pure block-ID remap (correctness-
// neutral).
// attn = v6 byte-exact (214 us; ledger: 7 failed restructures -- lockstep-
// wave L1 sharing is load-bearing, register-boxed at 4 blocks/CU).
// GEMM ledger: 3-buf vmcnt(6) pipeline -28us, 2-phase dbuf -22us; split-K +
// WN residency levers +41us total. Occupancy >> overlap here.
// rel_shift fact: BD[i,j] = BDu[i, j+1023-i] for j <= i+1024; rest is masked.
// ---------------------------------------------------------------------------

typedef __bf16 bf16x8 __attribute__((ext_vector_type(8)));
typedef float f32x4 __attribute__((ext_vector_type(4)));

#define DEVI __device__ __forceinline__

DEVI unsigned short f2bf(float f) {
  union { float f; unsigned int u; } v;
  v.f = f;
  unsigned int u = v.u;
  u += 0x7fffu + ((u >> 16) & 1u);  // RNE
  return (unsigned short)(u >> 16);
}

// async global->LDS, 16 B per lane; lds dest is the wave-uniform base.
DEVI void load16(const unsigned short* g, unsigned short* l) {
  __builtin_amdgcn_global_load_lds(
      (const __attribute__((address_space(1))) unsigned int*)g,
      (__attribute__((address_space(3))) unsigned int*)l, 16, 0, 0);
}

// ---------------------------------------------------------------------------
// fused f32 -> bf16 convert for memories / word_embed / pos_embed
// ---------------------------------------------------------------------------
__global__ __launch_bounds__(256) void cvt_all_kernel(
    const float* __restrict__ mem, const float* __restrict__ we,
    const float* __restrict__ pe, unsigned short* __restrict__ catb,
    unsigned short* __restrict__ posb) {
  const int b = blockIdx.x;
  const float* in;
  unsigned short* out;
  int idx;
  if (b < 4096) {
    in = mem; out = catb; idx = b;
  } else if (b < 8192) {
    in = we; out = catb + (size_t)4096 * 1024; idx = b - 4096;
  } else {
    in = pe; out = posb; idx = b - 8192;
  }
  const size_t i = ((size_t)idx * 256 + threadIdx.x) * 4;
  float4 v = *(const float4*)(in + i);
  ushort4 o;
  o.x = f2bf(v.x);
  o.y = f2bf(v.y);
  o.z = f2bf(v.z);
  o.w = f2bf(v.w);
  *(ushort4*)(out + i) = o;
}

// ---------------------------------------------------------------------------
// fused transpose+convert for all 5 weight matrices: out[c][r] = bf16(in[r][c])
// block ranges: [0,768) W_qkv, [768,1024) W_r, [1024,1280) W_o,
// [1280,2304) W_ff1, [2304,3328) W_ff2
// ---------------------------------------------------------------------------
__global__ __launch_bounds__(256) void transpose_all_kernel(
    const float* __restrict__ Wqkv, const float* __restrict__ Wr,
    const float* __restrict__ Wo, const float* __restrict__ Wff1,
    const float* __restrict__ Wff2, unsigned short* __restrict__ Tqkv,
    unsigned short* __restrict__ Tr, unsigned short* __restrict__ To,
    unsigned short* __restrict__ Tff1, unsigned short* __restrict__ Tff2) {
  __shared__ unsigned short t[64][72];
  const int b = blockIdx.x;
  const float* in;
  unsigned short* out;
  int ntx, R, C, local;
  if (b < 768) {
    in = Wqkv; out = Tqkv; ntx = 48; R = 1024; C = 3072; local = b;
  } else if (b < 1024) {
    in = Wr; out = Tr; ntx = 16; R = 1024; C = 1024; local = b - 768;
  } else if (b < 1280) {
    in = Wo; out = To; ntx = 16; R = 1024; C = 1024; local = b - 1024;
  } else if (b < 2304) {
    in = Wff1; out = Tff1; ntx = 64; R = 1024; C = 4096; local = b - 1280;
  } else {
    in = Wff2; out = Tff2; ntx = 16; R = 4096; C = 1024; local = b - 2304;
  }
  const int r0 = (local / ntx) * 64, c0 = (local % ntx) * 64;
  const int tid = threadIdx.x;
#pragma unroll
  for (int it = 0; it < 4; ++it) {
    int f = tid + 256 * it;
    int r = f >> 4;
    int c4 = (f & 15) << 2;
    float4 v = *(const float4*)(in + (size_t)(r0 + r) * C + c0 + c4);
    t[c4 + 0][r] = f2bf(v.x);
    t[c4 + 1][r] = f2bf(v.y);
    t[c4 + 2][r] = f2bf(v.z);
    t[c4 + 3][r] = f2bf(v.w);
  }
  __syncthreads();
#pragma unroll
  for (int it = 0; it < 4; ++it) {
    int f = tid + 256 * it;
    int cc = f >> 4;
    int r4 = (f & 15) << 2;
    ushort4 o;
    o.x = t[cc][r4 + 0];
    o.y = t[cc][r4 + 1];
    o.z = t[cc][r4 + 2];
    o.w = t[cc][r4 + 3];
    *(ushort4*)(out + (size_t)(c0 + cc) * R + r0 + r4) = o;
  }
}

// ---------------------------------------------------------------------------
// 128xBN x64 MFMA GEMM, global_load_lds staging. WN=4 -> BN=128 (proven
// path); WN=2 -> BN=64; WN=1 -> BN=32 (thin GEMMs, more blocks). blockIdx.z
// = split-K slice: loop bound Ks, row stride K, slice offset z*Ks; partial=1
// stores raw f32 partials at outF + z*M*N (reduced in ln_sum_kernel).
// EPI 0: QKV scatter (K/V to fragment-major), flat 1280-block active grid
// with XCD-chunked swizzle (each XCD owns 160 contiguous tiles -> B-panel
// group L2-resident); EPI 1: R scatter (frag-major); EPI 2: bias/resid/relu.
// Fragment-major layout (per 64-row slab, stride 131072 shorts):
//   AC/BD-type: idx = (t16*2+half)*512 + (quad*16+l15)*8 + e
//               value = X[row=t16*16+l15][col=half*32+quad*8+e]
//   PV-type V:  idx = jt*8192 + (ks*4+nto)*512 + (quad*16+l15)*8 + e
//               value = V[j=jt*128+ks*32+quad*8+e][d=nto*16+l15]
// ---------------------------------------------------------------------------
struct GemmArgs {
  const unsigned short* A;   // bf16 [M][K]
  const unsigned short* Bt;  // bf16 [N][K]
  int Ks;                    // K-loop extent (== K unless split-K)
  int M, N, K;
  const float* p0;  // bias_q (EPI0) / bias (EPI2)
  const float* p1;  // bias_k (EPI0)
  const float* resid;
  float* outF;
  unsigned short* o0;  // QQ / Rf / bf16-out
  unsigned short* o1;  // QK
  unsigned short* o2;  // Kf
  unsigned short* o3;  // Vf
  int relu;
  int partial;  // EPI2: store raw f32 partial at outF + z*M*N
};

constexpr int BM = 128, BK = 64;

template <int EPI, int WN = 4>
__global__ __launch_bounds__(256, 4) void gemm_kernel(GemmArgs ga) {
  constexpr int BN_ = WN * 32;
  __shared__ __align__(16) unsigned short As[BM * BK];
  __shared__ __align__(16) unsigned short Bs[BN_ * BK];

  int m0, n0;
  if constexpr (EPI == 0) {
    // flat enumeration of the 1280 active tiles (skip q-cols x memory-rows),
    // XCD-chunked: flat = (b&7)*160 + (b>>3) (bijective, 1280 = 8*160).
    const int flat = (blockIdx.x & 7) * 160 + (blockIdx.x >> 3);
    int mt_, nt_;
    if (flat < 1024) {         // K/V columns: ntile 8..23, all 64 m-tiles
      mt_ = flat >> 4;
      nt_ = 8 + (flat & 15);
    } else {                   // q columns: ntile 0..7, m-tiles 32..63
      const int f2 = flat - 1024;
      mt_ = 32 + (f2 >> 3);
      nt_ = f2 & 7;
    }
    m0 = mt_ * 128;
    n0 = nt_ * 128;
  } else {
    n0 = blockIdx.x * BN_;
    m0 = blockIdx.y * BM;
  }
  const int bz = blockIdx.z;
  const int tid = threadIdx.x;
  const int lane = tid & 63;
  const int wv = tid >> 6;
  const int l15 = lane & 15;
  const int quad = lane >> 4;
  const int wm = wv & 1, wn = wv >> 1;
  const int K = ga.K;
  const int Ks = ga.Ks;
  const int r8 = lane >> 3;
  const int sc = (lane & 7) ^ r8;

  const f32x4 fzero = {0.f, 0.f, 0.f, 0.f};
  f32x4 acc[4][WN];
#pragma unroll
  for (int i = 0; i < 4; ++i)
#pragma unroll
    for (int j = 0; j < WN; ++j) acc[i][j] = fzero;

  const unsigned short* Ab =
      ga.A + (size_t)(m0 + 32 * wv + r8) * K + sc * 8 + (size_t)bz * Ks;
  const unsigned short* Bb =
      ga.Bt + (size_t)(n0 + (BN_ / 4) * wv + r8) * K + sc * 8 + (size_t)bz * Ks;
  const int h7 = l15 & 7;

  for (int k0 = 0; k0 < Ks; k0 += BK) {
    __syncthreads();
#pragma unroll
    for (int it = 0; it < 4; ++it)
      load16(Ab + (size_t)(8 * it) * K + k0, &As[(32 * wv + 8 * it) * 64]);
#pragma unroll
    for (int it = 0; it < BN_ / 32; ++it)
      load16(Bb + (size_t)(8 * it) * K + k0, &Bs[((BN_ / 4) * wv + 8 * it) * 64]);
    __syncthreads();
#pragma unroll
    for (int ks = 0; ks < 2; ++ks) {
      bf16x8 af[4], bg[WN];
#pragma unroll
      for (int mt = 0; mt < 4; ++mt)
        af[mt] = *(const bf16x8*)&As[(wm * 64 + mt * 16 + l15) * 64 +
                                     (((ks * 4 + quad) ^ h7) * 8)];
#pragma unroll
      for (int nt = 0; nt < WN; ++nt)
        bg[nt] = *(const bf16x8*)&Bs[(wn * (WN * 16) + nt * 16 + l15) * 64 +
                                     (((ks * 4 + quad) ^ h7) * 8)];
#pragma unroll
      for (int mt = 0; mt < 4; ++mt)
#pragma unroll
        for (int nt = 0; nt < WN; ++nt)
          acc[mt][nt] =
              __builtin_amdgcn_mfma_f32_16x16x32_bf16(af[mt], bg[nt], acc[mt][nt], 0, 0, 0);
    }
  }

#pragma unroll
  for (int mt = 0; mt < 4; ++mt) {
#pragma unroll
    for (int nt = 0; nt < WN; ++nt) {
#pragma unroll
      for (int r = 0; r < 4; ++r) {
        const int row = m0 + wm * 64 + mt * 16 + quad * 4 + r;
        const int col = n0 + wn * (WN * 16) + nt * 16 + l15;
        float val = acc[mt][nt][r];
        if constexpr (EPI == 0) {
          const int seq = row >> 2, b = row & 3;  // cat flat row = seq*BSZ + b
          if (col < 1024) {
            if (seq >= 1024) {
              const int nh = col >> 6, d = col & 63;
              const size_t o = ((size_t)((b * 16 + nh) * 1024 + (seq - 1024))) * 64 + d;
              ga.o0[o] = f2bf(val + ga.p0[col]);  // q + bias_q
              ga.o1[o] = f2bf(val + ga.p1[col]);  // q + bias_k
            }
          } else if (col < 2048) {
            // K -> fragment-major
            const int c = col - 1024, nh = c >> 6, d = c & 63, bn = b * 16 + nh;
            const size_t o = (size_t)bn * 131072 +
                             (size_t)(((seq >> 4) * 2 + (d >> 5)) * 512) +
                             ((((d >> 3) & 3) * 16 + (seq & 15)) * 8) + (d & 7);
            ga.o2[o] = f2bf(val);
          } else {
            // V -> fragment-major (PV-type)
            const int c = col - 2048, nh = c >> 6, d = c & 63, bn = b * 16 + nh;
            const size_t o = (size_t)bn * 131072 + (size_t)((seq >> 7) * 8192) +
                             ((((seq >> 5) & 3) * 4 + (d >> 4)) * 512) +
                             ((((seq >> 3) & 3) * 16 + (d & 15)) * 8) + (seq & 7);
            ga.o3[o] = f2bf(val);
          }
        } else if constexpr (EPI == 1) {
          // R -> fragment-major per head
          const int nh = col >> 6, d = col & 63, t = row;
          const size_t o = (size_t)nh * 131072 +
                           (size_t)(((t >> 4) * 2 + (d >> 5)) * 512) +
                           ((((d >> 3) & 3) * 16 + (t & 15)) * 8) + (d & 7);
          ga.o0[o] = f2bf(val);
        } else {
          if (ga.partial) {
            ga.outF[(size_t)bz * ((size_t)ga.M * ga.N) + (size_t)row * ga.N + col] = val;
          } else {
            if (ga.p0) val += ga.p0[col];
            if (ga.resid) val += ga.resid[(size_t)row * ga.N + col];
            if (ga.relu) val = fmaxf(val, 0.f);
            if (ga.outF) ga.outF[(size_t)row * ga.N + col] = val;
            if (ga.o0) ga.o0[(size_t)row * ga.N + col] = f2bf(val);
          }
        }
      }
    }
  }
}

// ---------------------------------------------------------------------------
// Flash attention with Transformer-XL relative-position term (v6, round-0
// byte-exact). Barrier-free; one wave per 16-row i-tile; 4 blocks/CU. All
// K/V/R B-operands are coalesced dwordx4 loads from fragment-major global
// slabs (L2-resident; block%8 == bn%8 keeps each XCD at 8 slabs). The 4
// waves of a block scan the same j-chunks in lockstep -> L1 line sharing.
// Fixed-max softmax; l reduced once at epilogue; P hop via wave-private LDS.
// ---------------------------------------------------------------------------
constexpr int P_LD = 136;            // p_s row stride (bf16 elems)
constexpr float CEXP = 0.18033688f;  // 0.125 * log2(e)

__global__ __launch_bounds__(256, 4) void attn_kernel(
    const unsigned short* __restrict__ QQ, const unsigned short* __restrict__ QK,
    const unsigned short* __restrict__ Kf, const unsigned short* __restrict__ Vf,
    const unsigned short* __restrict__ Rf, unsigned short* __restrict__ AVb) {
  __shared__ __align__(16) unsigned short p_s[4][16 * P_LD];

  const int tid = threadIdx.x;
  const int lane = tid & 63;
  const int wv = tid >> 6;
  const int l15 = lane & 15;
  const int quad = lane >> 4;
  const int bn = blockIdx.x;                   // (b,n): block%8 == bn%8 -> XCD locality
  const int iw = (blockIdx.y * 4 + wv) * 16;   // wave-private 16-row i-tile
  const int nh = bn & 15;
  const int bb = bn >> 4;
  unsigned short* pw = &p_s[wv][0];

  const unsigned short* kf = Kf + (size_t)bn * 131072;
  const unsigned short* vf = Vf + (size_t)bn * 131072;
  const unsigned short* rf = Rf + (size_t)nh * 131072;

  // Q fragments in registers: rows [iw, iw+16)
  const size_t qoff = (size_t)bn * (1024 * 64) + (size_t)(iw + l15) * 64;
  const bf16x8 qq0 = *(const bf16x8*)(QQ + qoff + quad * 8);
  const bf16x8 qq1 = *(const bf16x8*)(QQ + qoff + 32 + quad * 8);
  const bf16x8 qk0 = *(const bf16x8*)(QK + qoff + quad * 8);
  const bf16x8 qk1 = *(const bf16x8*)(QK + qoff + 32 + quad * 8);

  const f32x4 fzero = {0.f, 0.f, 0.f, 0.f};
  f32x4 o_acc[4];
#pragma unroll
  for (int i = 0; i < 4; ++i) o_acc[i] = fzero;
  float lsum[4] = {0.f, 0.f, 0.f, 0.f};

  const int lane8 = lane * 8;
  const int jmax = iw + 15 + 1024;  // beyond this, tiles are fully masked
  for (int j0 = 0; j0 <= jmax; j0 += 128) {
    // BDu: window base t16b = (j0 + 1008 - iw)/16; 9 fragment tiles, clamped
    const int t16b = (j0 >> 4) + 63 - (iw >> 4);
    f32x4 bd[9];
#pragma unroll
    for (int ct = 0; ct < 9; ++ct) {
      int tg = t16b + ct;
      tg = (tg < 127) ? tg : 127;  // rows >=2048 only feed masked cols
      const unsigned short* rb = rf + (size_t)(tg * 1024) + lane8;
      bf16x8 b0 = *(const bf16x8*)rb;
      bf16x8 b1 = *(const bf16x8*)(rb + 512);
      f32x4 c = fzero;
      c = __builtin_amdgcn_mfma_f32_16x16x32_bf16(qk0, b0, c, 0, 0, 0);
      c = __builtin_amdgcn_mfma_f32_16x16x32_bf16(qk1, b1, c, 0, 0, 0);
      bd[ct] = c;
    }

    // AC = (q+bias_q) @ K^T
    const int ntb = j0 >> 4;
    f32x4 sv[8];
#pragma unroll
    for (int nt = 0; nt < 8; ++nt) {
      const unsigned short* kb = kf + (size_t)((ntb + nt) * 1024) + lane8;
      bf16x8 b0 = *(const bf16x8*)kb;
      bf16x8 b1 = *(const bf16x8*)(kb + 512);
      f32x4 c = fzero;
      c = __builtin_amdgcn_mfma_f32_16x16x32_bf16(qq0, b0, c, 0, 0, 0);
      c = __builtin_amdgcn_mfma_f32_16x16x32_bf16(qq1, b1, c, 0, 0, 0);
      sv[nt] = c;
    }

    // rel-shift (in-quad rotate) + fixed-max exp + per-lane l accumulation
#pragma unroll
    for (int r = 0; r < 4; ++r) {
      const int il = quad * 4 + r;  // tile-local row
      const int u = l15 + 15 - il;  // 0..30
      const int srcl = (lane & 48) | (u & 15);
      float w[9];
#pragma unroll
      for (int ct = 0; ct < 9; ++ct) w[ct] = __shfl(bd[ct][r], srcl, 64);
      const int ig = iw + il;
#pragma unroll
      for (int nt = 0; nt < 8; ++nt) {
        const float bdv = (u & 16) ? w[nt + 1] : w[nt];
        const int jg = j0 + nt * 16 + l15;
        float p = exp2f((sv[nt][r] + bdv) * CEXP);
        p = (jg > ig + 1024) ? 0.f : p;  // select: garbage/NaN-safe
        lsum[r] += p;
        pw[il * P_LD + nt * 16 + l15] = f2bf(p);
      }
    }

    // O += P @ V (K-dim = 128); V fragments coalesced from global
    const unsigned short* vb = vf + (size_t)((j0 >> 7) * 8192) + lane8;
#pragma unroll
    for (int ks = 0; ks < 4; ++ks) {
      bf16x8 ap = *(const bf16x8*)&pw[l15 * P_LD + ks * 32 + quad * 8];
#pragma unroll
      for (int nto = 0; nto < 4; ++nto) {
        bf16x8 bv = *(const bf16x8*)(vb + (ks * 4 + nto) * 512);
        o_acc[nto] = __builtin_amdgcn_mfma_f32_16x16x32_bf16(ap, bv, o_acc[nto], 0, 0, 0);
      }
    }
  }

  // reduce l across the 16 lanes holding each row, then write O/l
  float linv[4];
#pragma unroll
  for (int r = 0; r < 4; ++r) {
    float l = lsum[r];
    l += __shfl_xor(l, 1, 64);
    l += __shfl_xor(l, 2, 64);
    l += __shfl_xor(l, 4, 64);
    l += __shfl_xor(l, 8, 64);
    linv[r] = 1.f / l;
  }
#pragma unroll
  for (int nto = 0; nto < 4; ++nto) {
#pragma unroll
    for (int r = 0; r < 4; ++r) {
      const int ig = iw + quad * 4 + r;
      const int d = nto * 16 + l15;
      const float val = o_acc[nto][r] * linv[r];
      AVb[(size_t)(ig * 4 + bb) * 1024 + nh * 64 + d] = f2bf(val);
    }
  }
}

// ---------------------------------------------------------------------------
// LayerNorm over rows of 1024 with fused split-K reduce:
// pre[c] = x0[c] + x1[c] + bias[c]? + resid[c]?; then normalize.
// ---------------------------------------------------------------------------
__global__ __launch_bounds__(256) void ln_sum_kernel(
    const float* __restrict__ x0, const float* __restrict__ x1,
    const float* __restrict__ bias, const float* __restrict__ resid,
    const float* __restrict__ g, const float* __restrict__ bta,
    float* __restrict__ outF, unsigned short* __restrict__ outB) {
  const int row = blockIdx.x;
  const int tid = threadIdx.x;
  const size_t off = (size_t)row * 1024 + tid * 4;
  float4 v = *(const float4*)(x0 + off);
  const float4 w = *(const float4*)(x1 + off);
  v.x += w.x; v.y += w.y; v.z += w.z; v.w += w.w;
  if (bias) {
    const float4 b = *(const float4*)(bias + tid * 4);
    v.x += b.x; v.y += b.y; v.z += b.z; v.w += b.w;
  }
  if (resid) {
    const float4 rr = *(const float4*)(resid + off);
    v.x += rr.x; v.y += rr.y; v.z += rr.z; v.w += rr.w;
  }
  float s = v.x + v.y + v.z + v.w;
  float ss = v.x * v.x + v.y * v.y + v.z * v.z + v.w * v.w;
#pragma unroll
  for (int off2 = 1; off2 < 64; off2 <<= 1) {
    s += __shfl_xor(s, off2, 64);
    ss += __shfl_xor(ss, off2, 64);
  }
  __shared__ float red[8];
  const int wv = tid >> 6;
  if ((tid & 63) == 0) {
    red[wv] = s;
    red[4 + wv] = ss;
  }
  __syncthreads();
  s = red[0] + red[1] + red[2] + red[3];
  ss = red[4] + red[5] + red[6] + red[7];
  const float mu = s * (1.f / 1024.f);
  const float var = ss * (1.f / 1024.f) - mu * mu;
  const float rs = rsqrtf(var + 1e-5f);
  const float vv[4] = {v.x, v.y, v.z, v.w};
#pragma unroll
  for (int u = 0; u < 4; ++u) {
    const int c = tid * 4 + u;
    const float y = (vv[u] - mu) * rs * g[c] + bta[c];
    if (outF) outF[(size_t)row * 1024 + c] = y;
    if (outB) outB[(size_t)row * 1024 + c] = f2bf(y);
  }
}

// ---------------------------------------------------------------------------
extern "C" void kernel_launch(void* const* d_in, const int* in_sizes, int n_in,
                              void* d_out, int out_size, void* d_ws, size_t ws_size,
                              hipStream_t stream) {
  (void)in_sizes; (void)n_in; (void)out_size; (void)ws_size;
  const float* word_embed = (const float*)d_in[0];
  const float* pos_embed = (const float*)d_in[1];
  const float* bias_q = (const float*)d_in[2];
  const float* bias_k = (const float*)d_in[3];
  const float* memories = (const float*)d_in[4];
  const float* W_qkv = (const float*)d_in[5];
  const float* W_r = (const float*)d_in[6];
  const float* W_o = (const float*)d_in[7];
  const float* ln1_g = (const float*)d_in[8];
  const float* ln1_b = (const float*)d_in[9];
  const float* W_ff1 = (const float*)d_in[10];
  const float* b_ff1 = (const float*)d_in[11];
  const float* W_ff2 = (const float*)d_in[12];
  const float* b_ff2 = (const float*)d_in[13];
  const float* ln2_g = (const float*)d_in[14];
  const float* ln2_b = (const float*)d_in[15];
  float* out = (float*)d_out;

  char* ws = (char*)d_ws;
  unsigned short* QQ = (unsigned short*)(ws + 0);           // 8 MB
  unsigned short* QK = (unsigned short*)(ws + 8388608);     // 8 MB
  unsigned short* Kf = (unsigned short*)(ws + 16777216);    // 16 MB (frag-major)
  unsigned short* Vf = (unsigned short*)(ws + 50331648);    // 16 MB (frag-major)
  unsigned short* Rf = (unsigned short*)(ws + 67108864);    // 4 MB (frag-major)
  unsigned short* AVb = (unsigned short*)(ws + 71303168);   // 8 MB
  float* OUT1 = (float*)(ws + 96468992);                    // 16 MB
  unsigned short* OUT1b = (unsigned short*)(ws + 113246208);  // 8 MB
  unsigned short* Wqkv_t = (unsigned short*)(ws + 121634816); // 6 MB
  unsigned short* Wr_t = (unsigned short*)(ws + 127926272);   // 2 MB
  unsigned short* Wo_t = (unsigned short*)(ws + 130023424);   // 2 MB
  unsigned short* Wff1_t = (unsigned short*)(ws + 132120576); // 8 MB
  unsigned short* Wff2_t = (unsigned short*)(ws + 140509184); // 8 MB
  unsigned short* Catb = (unsigned short*)(ws + 79691776);    // 16 MB (pre-attn)
  unsigned short* Posb = (unsigned short*)(ws + 96468992);    // aliases OUT1 (pre-LN1)
  unsigned short* H = (unsigned short*)(ws + 0);              // 32 MB, aliases QQ/QK/Kf
  // split-K partial buffers (f32, 2 x 16 MB each), in post-attn dead regions:
  float* Pwo = (float*)(ws + 33554432);   // 33.5..67.1 MB: free gap + Vf (dead post-attn)
  float* Pff = (float*)(ws + 50331648);   // 50.3..83.9 MB: Vf + Rf + AVb (dead post-Wo) + Catb head

  const dim3 blk(256);

  // fused prologue: 1 cvt launch + 1 transpose launch
  cvt_all_kernel<<<10240, blk, 0, stream>>>(memories, word_embed, pos_embed, Catb, Posb);
  transpose_all_kernel<<<3328, blk, 0, stream>>>(W_qkv, W_r, W_o, W_ff1, W_ff2,
                                                 Wqkv_t, Wr_t, Wo_t, Wff1_t, Wff2_t);

  // QKV projection: M=8192, N=3072, K=1024; flat 1280-block active grid,
  // XCD-chunked swizzle
  {
    GemmArgs a{};
    a.A = Catb;
    a.Bt = Wqkv_t;
    a.M = 8192; a.N = 3072; a.K = 1024; a.Ks = 1024;
    a.p0 = bias_q; a.p1 = bias_k;
    a.o0 = QQ; a.o1 = QK; a.o2 = Kf; a.o3 = Vf;
    gemm_kernel<0><<<dim3(1280), blk, 0, stream>>>(a);
  }
  // R projection: M=2048, N=1024, K=1024 -> fragment-major per head
  // WN=1 (BN=32): 512 blocks = 2/CU
  {
    GemmArgs a{};
    a.A = Posb;
    a.Bt = Wr_t;
    a.M = 2048; a.N = 1024; a.K = 1024; a.Ks = 1024;
    a.o0 = Rf;
    gemm_kernel<1, 1><<<dim3(32, 16), blk, 0, stream>>>(a);
  }

  // attention: grid (bn=64, itile=16), 1024 blocks, 4/CU, barrier-free
  attn_kernel<<<dim3(64, 16), blk, 0, stream>>>(QQ, QK, Kf, Vf, Rf, AVb);

  // W_o projection, split-K=2 (1024 blocks, 4/CU): raw partials -> Pwo
  {
    GemmArgs a{};
    a.A = AVb;
    a.Bt = Wo_t;
    a.M = 4096; a.N = 1024; a.K = 1024; a.Ks = 512;
    a.outF = Pwo;
    a.partial = 1;
    gemm_kernel<2, 2><<<dim3(16, 32, 2), blk, 0, stream>>>(a);
  }
  // LN1 with fused reduce: P0+P1 + word_embed resid
  ln_sum_kernel<<<4096, blk, 0, stream>>>(Pwo, Pwo + (size_t)4096 * 1024, nullptr,
                                          word_embed, ln1_g, ln1_b, OUT1, OUT1b);

  // FF1 (BN=128, 1024 blocks)
  {
    GemmArgs a{};
    a.A = OUT1b;
    a.Bt = Wff1_t;
    a.M = 4096; a.N = 4096; a.K = 1024; a.Ks = 1024;
    a.p0 = b_ff1;
    a.relu = 1;
    a.o0 = H;
    gemm_kernel<2><<<dim3(32, 32), blk, 0, stream>>>(a);
  }
  // FF2, split-K=2 (1024 blocks, 4/CU, K=2048 each): raw partials -> Pff
  {
    GemmArgs a{};
    a.A = H;
    a.Bt = Wff2_t;
    a.M = 4096; a.N = 1024; a.K = 4096; a.Ks = 2048;
    a.outF = Pff;
    a.partial = 1;
    gemm_kernel<2, 2><<<dim3(16, 32, 2), blk, 0, stream>>>(a);
  }
  // LN2 with fused reduce: Q0+Q1 + b_ff2 + OUT1 resid
  ln_sum_kernel<<<4096, blk, 0, stream>>>(Pff, Pff + (size_t)4096 * 1024, b_ff2,
                                          OUT1, ln2_g, ln2_b, out, nullptr);
}